// Round 19
// baseline (250.700 us; speedup 1.0000x reference)
//
#include <hip/hip_runtime.h>
#include <hip/hip_bf16.h>

#define N_NODES 20000
#define E_EDGES 320000

typedef __attribute__((ext_vector_type(8))) short s8v;
typedef __attribute__((ext_vector_type(4))) float f4v;

__device__ __forceinline__ float lrelu(float v){ return v > 0.f ? v : 0.2f * v; }

__device__ __forceinline__ float bitf(unsigned short u){
  union { unsigned int i; float f; } v; v.i = ((unsigned int)u) << 16; return v.f;
}
__device__ __forceinline__ float4 bf4(const unsigned short* p){
  ushort4 u = *(const ushort4*)p;
  return make_float4(bitf(u.x), bitf(u.y), bitf(u.z), bitf(u.w));
}
__device__ __forceinline__ unsigned short bfhi(float v){
  union{float f; unsigned u;} a; a.f = v;
  unsigned r = a.u + 0x7FFFu + ((a.u >> 16) & 1u);
  return (unsigned short)(r >> 16);
}
__device__ __forceinline__ float bf2f(unsigned short h){
  union{unsigned u; float f;} a; a.u = ((unsigned)h) << 16; return a.f;
}
// split pair (v0,v1) into packed-bf16 hi word and lo word (RNE)
__device__ __forceinline__ void split2(float v0, float v1, unsigned& hu, unsigned& lu){
  __hip_bfloat162 h2 = __float22bfloat162_rn(make_float2(v0, v1));
  unsigned h; __builtin_memcpy(&h, &h2, 4);
  union{unsigned u; float f;} c0, c1;
  c0.u = h << 16;
  c1.u = h & 0xFFFF0000u;
  __hip_bfloat162 l2 = __float22bfloat162_rn(make_float2(v0 - c0.f, v1 - c1.f));
  unsigned l; __builtin_memcpy(&l, &l2, 4);
  hu = h; lu = l;
}
// async global->LDS, 16B per lane; lds base must be wave-uniform
__device__ __forceinline__ void gl_lds16(const void* g, void* l){
  __builtin_amdgcn_global_load_lds(
      (const __attribute__((address_space(1))) unsigned int*)g,
      (__attribute__((address_space(3))) unsigned int*)l, 16, 0, 0);
}

// ---------------- CSR build ----------------
__global__ __launch_bounds__(256) void k_count(const int* __restrict__ dst, int* __restrict__ deg, int E){
  int e = blockIdx.x * 256 + threadIdx.x;
  if (e < E) atomicAdd(&deg[dst[e]], 1);
}

// parallel scan stage 1: per-block exclusive scan + block sums (wave shfl scan)
__global__ __launch_bounds__(256) void k_scan1(const int* __restrict__ deg, int* __restrict__ off,
                                               int* __restrict__ bsum, int n){
  int b = blockIdx.x, t = threadIdx.x;
  int i = b * 256 + t;
  int lane = t & 63, w = t >> 6;
  int d = (i < n) ? deg[i] : 0;
  int x = d;
#pragma unroll
  for (int o = 1; o < 64; o <<= 1){
    int v = __shfl_up(x, o, 64);
    if (lane >= o) x += v;
  }
  __shared__ int ws[4];
  if (lane == 63) ws[w] = x;
  __syncthreads();
  int add = 0;
#pragma unroll
  for (int k = 0; k < 4; ++k) if (k < w) add += ws[k];
  x += add;
  if (i < n) off[i] = x - d;           // exclusive within block
  if (t == 255) bsum[b] = x;           // block total
}

// stage 2: tiny serial scan of block sums; also writes off[n] = total
__global__ __launch_bounds__(64) void k_scan2(int* __restrict__ bsum, int nb, int* __restrict__ offN){
  if (threadIdx.x == 0){
    int a = 0;
    for (int i = 0; i < nb; ++i){ int v = bsum[i]; bsum[i] = a; a += v; }
    *offN = a;
  }
}

// stage 3: add block bases; init cur
__global__ __launch_bounds__(256) void k_scan3(int* __restrict__ off, const int* __restrict__ bsum,
                                               int* __restrict__ cur, int n){
  int b = blockIdx.x, i = b * 256 + threadIdx.x;
  if (i < n){ off[i] += bsum[b]; cur[i] = 0; }
}

__global__ __launch_bounds__(256) void k_fill(const int* __restrict__ src, const int* __restrict__ dst,
                       const int* __restrict__ ety, const float* __restrict__ ew,
                       const int* __restrict__ off, int* __restrict__ cur,
                       int* __restrict__ csrc, int* __restrict__ cet, float* __restrict__ cw, int E){
  int e = blockIdx.x * 256 + threadIdx.x;
  if (e < E){
    int d = dst[e];
    int p = atomicAdd(&cur[d], 1);
    int i = off[d] + p;
    csrc[i] = src[e];
    cet[i]  = ety[e];
    cw[i]   = ew[e];
  }
}

// ---------------- combined weight prep: all three weight matrices in ONE dispatch ----------------
__global__ __launch_bounds__(64) void k_prep3(
    const float* __restrict__ Wp, const float* __restrict__ W1, const float* __restrict__ W2,
    unsigned short* __restrict__ BpP, unsigned short* __restrict__ Bp1, unsigned short* __restrict__ Bp2)
{
  int ktg = blockIdx.x;
  const float* W; unsigned short* Bp; int kt; int K;
  if (ktg < 28)      { W = Wp; Bp = BpP; kt = ktg;      K = 896; }
  else if (ktg < 36) { W = W1; Bp = Bp1; kt = ktg - 28; K = 256; }
  else               { W = W2; Bp = Bp2; kt = ktg - 36; K = 256; }
  int n = blockIdx.y * 64 + threadIdx.x;
  unsigned short hi[32], lo[32];
#pragma unroll
  for (int kk = 0; kk < 32; ++kk){
    float v = W[(size_t)(kt * 32 + kk) * 256 + n];   // coalesced over n
    unsigned short h = bfhi(v);
    hi[kk] = h;
    lo[kk] = bfhi(v - bf2f(h));
  }
  size_t plane = (size_t)(K >> 5) * 256 * 32;
  size_t b = ((size_t)kt * 256 + n) * 32;
#pragma unroll
  for (int kk = 0; kk < 32; ++kk){
    Bp[b + kk]         = hi[kk];
    Bp[plane + b + kk] = lo[kk];
  }
}

// ---------------- proj GEMM: R8/R12 kernel, single dispatch (62us; frozen) ----------------
__global__ __launch_bounds__(128, 4) void k_mmp(
    const float* __restrict__ A, const unsigned short* __restrict__ Bp,
    const float* __restrict__ bias, unsigned short* __restrict__ Cout)
{
  constexpr int KT = 28;
  __shared__ unsigned short AhB[2][32 * 40];
  __shared__ unsigned short AlB[2][32 * 40];

  const int tid  = threadIdx.x;
  const int lane = tid & 63;
  const int wn   = tid >> 6;
  const int l15  = lane & 15;
  const int kg   = lane >> 4;
  const int m0   = blockIdx.x * 32;
  const int n0   = blockIdx.y * 128;
  const size_t planeB = (size_t)KT * 256 * 32;

  f4v acc[2][4];
#pragma unroll
  for (int f = 0; f < 2; ++f)
#pragma unroll
    for (int g = 0; g < 4; ++g)
#pragma unroll
      for (int r = 0; r < 4; ++r) acc[f][g][r] = 0.f;

  const int arow = tid >> 2;          // 0..31 staged row
  const int aj   = tid & 3;           // k-chunk
  const int gr   = m0 + arow;

  auto loadA = [&](float* v, int kt){
    int c = kt * 32 + aj * 8;         // 8-chunks never straddle c=128
    const float* sp; float sc;
    if (c < 128){ sp = A + (size_t)gr * 896 + (768 + c); sc = 1.f; }
    else        { sp = A + (size_t)gr * 896 + (c - 128); sc = 3.f; }
    float4 f0 = *(const float4*)sp;
    float4 f1 = *(const float4*)(sp + 4);
    v[0]=f0.x*sc; v[1]=f0.y*sc; v[2]=f0.z*sc; v[3]=f0.w*sc;
    v[4]=f1.x*sc; v[5]=f1.y*sc; v[6]=f1.z*sc; v[7]=f1.w*sc;
  };
  auto writeLDS = [&](const float* v, int buf){
    union { unsigned u[4]; s8v s; } hv, lv;
#pragma unroll
    for (int p = 0; p < 4; ++p)
      split2(v[2*p], v[2*p+1], hv.u[p], lv.u[p]);
    *(s8v*)&AhB[buf][arow * 40 + aj * 8] = hv.s;
    *(s8v*)&AlB[buf][arow * 40 + aj * 8] = lv.s;
  };

  float av[8];
  loadA(av, 0);
  writeLDS(av, 0);
  loadA(av, 1);

  int cur = 0;
#pragma unroll 1
  for (int kt = 0; kt < KT; ++kt){
    __syncthreads();                       // LDS[cur] ready; LDS[cur^1] free
    if (kt + 1 < KT) writeLDS(av, cur ^ 1);
    if (kt + 2 < KT) loadA(av, kt + 2);
    s8v bh[4], bl[4];
#pragma unroll
    for (int g = 0; g < 4; ++g){
      const unsigned short* bp2 = Bp + ((size_t)kt * 256 + n0 + wn * 64 + g * 16 + l15) * 32 + kg * 8;
      bh[g] = *(const s8v*)bp2;
      bl[g] = *(const s8v*)(bp2 + planeB);
    }
    s8v ah[2], al[2];
#pragma unroll
    for (int f = 0; f < 2; ++f){
      int row = f * 16 + l15;
      ah[f] = *(const s8v*)&AhB[cur][row * 40 + kg * 8];
      al[f] = *(const s8v*)&AlB[cur][row * 40 + kg * 8];
    }
#pragma unroll
    for (int f = 0; f < 2; ++f)
#pragma unroll
      for (int g = 0; g < 4; ++g){
        acc[f][g] = __builtin_amdgcn_mfma_f32_16x16x32_bf16(ah[f], bh[g], acc[f][g], 0, 0, 0);
        acc[f][g] = __builtin_amdgcn_mfma_f32_16x16x32_bf16(ah[f], bl[g], acc[f][g], 0, 0, 0);
        acc[f][g] = __builtin_amdgcn_mfma_f32_16x16x32_bf16(al[f], bh[g], acc[f][g], 0, 0, 0);
      }
    cur ^= 1;
  }

#pragma unroll
  for (int f = 0; f < 2; ++f){
#pragma unroll
    for (int g = 0; g < 4; ++g){
      int col = n0 + wn * 64 + g * 16 + l15;
      float bb = bias[col];
#pragma unroll
      for (int r = 0; r < 4; ++r){
        int row = m0 + f * 16 + kg * 4 + r;
        float v = fmaxf(acc[f][g][r] + bb, 0.f);
        Cout[(size_t)row * 256 + col] = bfhi(v);
      }
    }
  }
}

// ---------------- hidden GEMM: global_load_lds + pre-split planes (BM=32, BN=256) ------------
__global__ __launch_bounds__(256, 2) void k_mmh(
    const unsigned short* __restrict__ Ahi, const unsigned short* __restrict__ Alo,
    const unsigned short* __restrict__ Bp, unsigned short* __restrict__ Cout,
    const float* __restrict__ attS, const float* __restrict__ attD,
    float* __restrict__ aS, float* __restrict__ aD)
{
  constexpr int KT = 8;
  __shared__ alignas(16) unsigned char Abuf[2][4096];

  const int tid  = threadIdx.x;
  const int lane = tid & 63;
  const int w    = tid >> 6;      // wave id = head
  const int l15  = lane & 15;
  const int kg   = lane >> 4;
  const int m0   = blockIdx.x * 32;
  const size_t planeB = (size_t)KT * 256 * 32;

  f4v acc[2][4];
#pragma unroll
  for (int f = 0; f < 2; ++f)
#pragma unroll
    for (int g = 0; g < 4; ++g)
#pragma unroll
      for (int r = 0; r < 4; ++r) acc[f][g][r] = 0.f;

  auto stage = [&](int buf, int kt){
    int s   = tid;
    int p   = s >> 7;
    int sp  = s & 127;
    int row = sp >> 2;
    int kcp = sp & 3;
    int kc  = kcp ^ (row & 3);        // inverse swizzle on SOURCE
    const unsigned short* basep = p ? Alo : Ahi;
    const unsigned short* gp = basep + (size_t)(m0 + row) * 256 + kt * 32 + kc * 8;
    gl_lds16(gp, &Abuf[buf][w * 1024]);
  };
  auto readFrags = [&](s8v* ah, s8v* al, int buf){
#pragma unroll
    for (int f = 0; f < 2; ++f){
      int row = f * 16 + l15;
      int kc  = kg ^ (row & 3);       // swizzled read
      ah[f] = *(const s8v*)&Abuf[buf][row * 64 + kc * 16];
      al[f] = *(const s8v*)&Abuf[buf][2048 + row * 64 + kc * 16];
    }
  };
  auto loadB = [&](s8v* bh, s8v* bl, int kt){
#pragma unroll
    for (int g = 0; g < 4; ++g){
      const unsigned short* bp2 = Bp + ((size_t)kt * 256 + w * 64 + g * 16 + l15) * 32 + kg * 8;
      bh[g] = *(const s8v*)bp2;
      bl[g] = *(const s8v*)(bp2 + planeB);
    }
  };
  auto doMFMA = [&](const s8v* ah, const s8v* al, const s8v* bh, const s8v* bl){
#pragma unroll
    for (int f = 0; f < 2; ++f)
#pragma unroll
      for (int g = 0; g < 4; ++g){
        acc[f][g] = __builtin_amdgcn_mfma_f32_16x16x32_bf16(ah[f], bh[g], acc[f][g], 0, 0, 0);
        acc[f][g] = __builtin_amdgcn_mfma_f32_16x16x32_bf16(ah[f], bl[g], acc[f][g], 0, 0, 0);
        acc[f][g] = __builtin_amdgcn_mfma_f32_16x16x32_bf16(al[f], bh[g], acc[f][g], 0, 0, 0);
      }
  };

  s8v bh[4], bl[4];
  stage(0, 0);
  loadB(bh, bl, 0);
  __syncthreads();

  int cur = 0;
#pragma unroll 1
  for (int kt = 0; kt < KT; ++kt){
    if (kt + 1 < KT) stage(cur ^ 1, kt + 1);   // async, zero regs
    s8v ah[2], al[2];
    readFrags(ah, al, cur);
    s8v nbh[4], nbl[4];
    if (kt + 1 < KT) loadB(nbh, nbl, kt + 1);
    doMFMA(ah, al, bh, bl);
    if (kt + 1 < KT){
#pragma unroll
      for (int g = 0; g < 4; ++g){ bh[g] = nbh[g]; bl[g] = nbl[g]; }
    }
    __syncthreads();
    cur ^= 1;
  }

#pragma unroll
  for (int f = 0; f < 2; ++f){
#pragma unroll
    for (int g = 0; g < 4; ++g){
      int col = w * 64 + g * 16 + l15;
#pragma unroll
      for (int r = 0; r < 4; ++r){
        int row = m0 + f * 16 + kg * 4 + r;
        Cout[(size_t)row * 256 + col] = bfhi(acc[f][g][r]);
      }
    }
  }

  {
    const int head = w;
    float sv[4], dv[4];
#pragma unroll
    for (int g = 0; g < 4; ++g){
      int col = w * 64 + g * 16 + l15;
      sv[g] = attS[col];
      dv[g] = attD[col];
    }
#pragma unroll
    for (int f = 0; f < 2; ++f){
#pragma unroll
      for (int r = 0; r < 4; ++r){
        float ps = acc[f][0][r]*sv[0] + acc[f][1][r]*sv[1] + acc[f][2][r]*sv[2] + acc[f][3][r]*sv[3];
        float pd = acc[f][0][r]*dv[0] + acc[f][1][r]*dv[1] + acc[f][2][r]*dv[2] + acc[f][3][r]*dv[3];
#pragma unroll
        for (int mm = 1; mm < 16; mm <<= 1){
          ps += __shfl_xor(ps, mm, 64);
          pd += __shfl_xor(pd, mm, 64);
        }
        int row = m0 + f * 16 + kg * 4 + r;
        if (l15 == 0){
          aS[(size_t)row * 4 + head] = ps;
          aD[(size_t)row * 4 + head] = pd;
        }
      }
    }
  }
}

// ---------------- first aggregation: h1 = h0[n] + Σ h0[src] + Σ_t wsum_t*rel[t]; 16-deep MLP -----
__global__ __launch_bounds__(256) void k_agg(
    const unsigned short* __restrict__ h0, const int* __restrict__ off,
    const int* __restrict__ csrc, const int* __restrict__ cet, const float* __restrict__ cw,
    const float* __restrict__ rel,
    unsigned short* __restrict__ h1hi, unsigned short* __restrict__ h1lo, int N)
{
  __shared__ int srcs[4][128];
  const int wv = threadIdx.x >> 6;
  const int n  = blockIdx.x * 4 + wv;
  if (n >= N) return;
  const int lane = threadIdx.x & 63;
  const int c0 = lane * 4;
  const int s0 = off[n], s1 = off[n + 1];
  const int deg = s1 - s0;
  const int nc = deg < 128 ? deg : 128;

  float w0=0.f, w1=0.f, w2=0.f, w3=0.f, w4=0.f;
  for (int base = 0; base < deg; base += 64){
    int ci = base + lane;
    if (ci < deg){
      int e = s0 + ci;
      int s = csrc[e];
      int t = cet[e];
      float wg = cw[e];
      if (ci < 128) srcs[wv][ci] = s;
      w0 += (t == 0) ? wg : 0.f;
      w1 += (t == 1) ? wg : 0.f;
      w2 += (t == 2) ? wg : 0.f;
      w3 += (t == 3) ? wg : 0.f;
      w4 += (t == 4) ? wg : 0.f;
    }
  }
#pragma unroll
  for (int mm = 1; mm < 64; mm <<= 1){
    w0 += __shfl_xor(w0, mm, 64);
    w1 += __shfl_xor(w1, mm, 64);
    w2 += __shfl_xor(w2, mm, 64);
    w3 += __shfl_xor(w3, mm, 64);
    w4 += __shfl_xor(w4, mm, 64);
  }
  asm volatile("s_waitcnt lgkmcnt(0)" ::: "memory");   // srcs visible in-wave

  float4 acc = bf4(&h0[(size_t)n * 256 + c0]);
  { float4 R = *(const float4*)&rel[0 * 256 + c0];
    acc.x = fmaf(w0, R.x, acc.x); acc.y = fmaf(w0, R.y, acc.y);
    acc.z = fmaf(w0, R.z, acc.z); acc.w = fmaf(w0, R.w, acc.w); }
  { float4 R = *(const float4*)&rel[1 * 256 + c0];
    acc.x = fmaf(w1, R.x, acc.x); acc.y = fmaf(w1, R.y, acc.y);
    acc.z = fmaf(w1, R.z, acc.z); acc.w = fmaf(w1, R.w, acc.w); }
  { float4 R = *(const float4*)&rel[2 * 256 + c0];
    acc.x = fmaf(w2, R.x, acc.x); acc.y = fmaf(w2, R.y, acc.y);
    acc.z = fmaf(w2, R.z, acc.z); acc.w = fmaf(w2, R.w, acc.w); }
  { float4 R = *(const float4*)&rel[3 * 256 + c0];
    acc.x = fmaf(w3, R.x, acc.x); acc.y = fmaf(w3, R.y, acc.y);
    acc.z = fmaf(w3, R.z, acc.z); acc.w = fmaf(w3, R.w, acc.w); }
  { float4 R = *(const float4*)&rel[4 * 256 + c0];
    acc.x = fmaf(w4, R.x, acc.x); acc.y = fmaf(w4, R.y, acc.y);
    acc.z = fmaf(w4, R.z, acc.z); acc.w = fmaf(w4, R.w, acc.w); }

  int e = 0;
  for (; e + 15 < nc; e += 16){
    int sx[16];
#pragma unroll
    for (int j = 0; j < 16; ++j) sx[j] = srcs[wv][e + j];
    float4 xv16[16];
#pragma unroll
    for (int j = 0; j < 16; ++j) xv16[j] = bf4(&h0[(size_t)sx[j] * 256 + c0]);
    float tx = 0.f, ty = 0.f, tz = 0.f, tw = 0.f;
#pragma unroll
    for (int j = 0; j < 16; ++j){
      tx += xv16[j].x; ty += xv16[j].y; tz += xv16[j].z; tw += xv16[j].w;
    }
    acc.x += tx; acc.y += ty; acc.z += tz; acc.w += tw;
  }
  for (; e + 7 < nc; e += 8){
    int sx[8];
#pragma unroll
    for (int j = 0; j < 8; ++j) sx[j] = srcs[wv][e + j];
    float4 xv8[8];
#pragma unroll
    for (int j = 0; j < 8; ++j) xv8[j] = bf4(&h0[(size_t)sx[j] * 256 + c0]);
    float tx = 0.f, ty = 0.f, tz = 0.f, tw = 0.f;
#pragma unroll
    for (int j = 0; j < 8; ++j){
      tx += xv8[j].x; ty += xv8[j].y; tz += xv8[j].z; tw += xv8[j].w;
    }
    acc.x += tx; acc.y += ty; acc.z += tz; acc.w += tw;
  }
  for (; e < nc; ++e){
    int s = srcs[wv][e];
    float4 xv = bf4(&h0[(size_t)s * 256 + c0]);
    acc.x += xv.x; acc.y += xv.y; acc.z += xv.z; acc.w += xv.w;
  }
  for (int ci = 128; ci < deg; ++ci){    // overflow (wsum already complete)
    int s = csrc[s0 + ci];
    float4 xv = bf4(&h0[(size_t)s * 256 + c0]);
    acc.x += xv.x; acc.y += xv.y; acc.z += xv.z; acc.w += xv.w;
  }

  ushort4 hi, lo;
  { unsigned short h;
    h = bfhi(acc.x); hi.x = h; lo.x = bfhi(acc.x - bf2f(h));
    h = bfhi(acc.y); hi.y = h; lo.y = bfhi(acc.y - bf2f(h));
    h = bfhi(acc.z); hi.z = h; lo.z = bfhi(acc.z - bf2f(h));
    h = bfhi(acc.w); hi.w = h; lo.w = bfhi(acc.w - bf2f(h));
  }
  *(ushort4*)&h1hi[(size_t)n * 256 + c0] = hi;
  *(ushort4*)&h1lo[(size_t)n * 256 + c0] = lo;
}

// ---------------- GAT edge softmax + aggregate; 16-deep gather MLP ----------------
template<bool SCORE>
__global__ __launch_bounds__(256) void k_gat(
    const unsigned short* __restrict__ xh, const float* __restrict__ aS, const float* __restrict__ aD,
    const int* __restrict__ off, const int* __restrict__ csrc,
    const float* __restrict__ bias,
    unsigned short* __restrict__ h1hi, unsigned short* __restrict__ h1lo,
    const float* __restrict__ Wo, const float* __restrict__ bo, float* __restrict__ out, int N)
{
  __shared__ float4 exs[4][128];
  __shared__ int   srcs[4][128];
  const int wv   = threadIdx.x >> 6;
  const int n    = blockIdx.x * 4 + wv;
  if (n >= N) return;
  const int lane = threadIdx.x & 63;
  const int head = lane >> 4;
  const int c0   = lane * 4;
  const int s0 = off[n], s1 = off[n + 1];
  const int deg = s1 - s0;
  const int nc = deg < 128 ? deg : 128;

  float4 ad4 = *(const float4*)&aD[(size_t)n * 4];
  float4 asf = *(const float4*)&aS[(size_t)n * 4];
  float4 aself;
  aself.x = lrelu(asf.x + ad4.x); aself.y = lrelu(asf.y + ad4.y);
  aself.z = lrelu(asf.z + ad4.z); aself.w = lrelu(asf.w + ad4.w);
  float4 q = aself;

  for (int base = 0; base < deg; base += 64){
    int ci = base + lane;
    if (ci < deg){
      int s = csrc[s0 + ci];
      float4 av = *(const float4*)&aS[(size_t)s * 4];
      float4 al4;
      al4.x = lrelu(av.x + ad4.x); al4.y = lrelu(av.y + ad4.y);
      al4.z = lrelu(av.z + ad4.z); al4.w = lrelu(av.w + ad4.w);
      q.x = fmaxf(q.x, al4.x); q.y = fmaxf(q.y, al4.y);
      q.z = fmaxf(q.z, al4.z); q.w = fmaxf(q.w, al4.w);
      if (ci < 128){ srcs[wv][ci] = s; exs[wv][ci] = al4; }
    }
  }
#pragma unroll
  for (int mm = 1; mm < 64; mm <<= 1){
    q.x = fmaxf(q.x, __shfl_xor(q.x, mm, 64));
    q.y = fmaxf(q.y, __shfl_xor(q.y, mm, 64));
    q.z = fmaxf(q.z, __shfl_xor(q.z, mm, 64));
    q.w = fmaxf(q.w, __shfl_xor(q.w, mm, 64));
  }
  asm volatile("s_waitcnt lgkmcnt(0)" ::: "memory");

  float4 den4 = make_float4(0.f, 0.f, 0.f, 0.f);
  for (int ci = lane; ci < nc; ci += 64){
    float4 a = exs[wv][ci];
    float4 e4;
    e4.x = __expf(a.x - q.x); e4.y = __expf(a.y - q.y);
    e4.z = __expf(a.z - q.z); e4.w = __expf(a.w - q.w);
    exs[wv][ci] = e4;
    den4.x += e4.x; den4.y += e4.y; den4.z += e4.z; den4.w += e4.w;
  }
#pragma unroll
  for (int mm = 1; mm < 64; mm <<= 1){
    den4.x += __shfl_xor(den4.x, mm, 64);
    den4.y += __shfl_xor(den4.y, mm, 64);
    den4.z += __shfl_xor(den4.z, mm, 64);
    den4.w += __shfl_xor(den4.w, mm, 64);
  }
  asm volatile("s_waitcnt lgkmcnt(0)" ::: "memory");

  const float mh  = head == 0 ? q.x : (head == 1 ? q.y : (head == 2 ? q.z : q.w));
  const float adh = head == 0 ? ad4.x : (head == 1 ? ad4.y : (head == 2 ? ad4.z : ad4.w));
  const float aselfh = head == 0 ? aself.x : (head == 1 ? aself.y : (head == 2 ? aself.z : aself.w));
  float den = (head == 0 ? den4.x : (head == 1 ? den4.y : (head == 2 ? den4.z : den4.w)));
  float exself = __expf(aselfh - mh);
  den += exself;

  float4 xv = bf4(&xh[(size_t)n * 256 + c0]);
  float4 acc;
  acc.x = exself * xv.x; acc.y = exself * xv.y; acc.z = exself * xv.z; acc.w = exself * xv.w;

  const float* exw = (const float*)&exs[wv][0];
  int e = 0;
  for (; e + 15 < nc; e += 16){
    int sx[16];
    float ex16[16];
#pragma unroll
    for (int j = 0; j < 16; ++j){
      sx[j]   = srcs[wv][e + j];
      ex16[j] = exw[(e + j) * 4 + head];
    }
    float4 xv16[16];
#pragma unroll
    for (int j = 0; j < 16; ++j) xv16[j] = bf4(&xh[(size_t)sx[j] * 256 + c0]);
    float tx = 0.f, ty = 0.f, tz = 0.f, tw = 0.f;
#pragma unroll
    for (int j = 0; j < 16; ++j){
      tx = fmaf(ex16[j], xv16[j].x, tx);
      ty = fmaf(ex16[j], xv16[j].y, ty);
      tz = fmaf(ex16[j], xv16[j].z, tz);
      tw = fmaf(ex16[j], xv16[j].w, tw);
    }
    acc.x += tx; acc.y += ty; acc.z += tz; acc.w += tw;
  }
  for (; e + 7 < nc; e += 8){
    int sx[8];
    float ex8[8];
#pragma unroll
    for (int j = 0; j < 8; ++j){
      sx[j]  = srcs[wv][e + j];
      ex8[j] = exw[(e + j) * 4 + head];
    }
    float4 xv8[8];
#pragma unroll
    for (int j = 0; j < 8; ++j) xv8[j] = bf4(&xh[(size_t)sx[j] * 256 + c0]);
    float tx = 0.f, ty = 0.f, tz = 0.f, tw = 0.f;
#pragma unroll
    for (int j = 0; j < 8; ++j){
      tx = fmaf(ex8[j], xv8[j].x, tx);
      ty = fmaf(ex8[j], xv8[j].y, ty);
      tz = fmaf(ex8[j], xv8[j].z, tz);
      tw = fmaf(ex8[j], xv8[j].w, tw);
    }
    acc.x += tx; acc.y += ty; acc.z += tz; acc.w += tw;
  }
  for (; e < nc; ++e){
    int s = srcs[wv][e];
    float ef = exw[e * 4 + head];
    float4 x2 = bf4(&xh[(size_t)s * 256 + c0]);
    acc.x = fmaf(ef, x2.x, acc.x);
    acc.y = fmaf(ef, x2.y, acc.y);
    acc.z = fmaf(ef, x2.z, acc.z);
    acc.w = fmaf(ef, x2.w, acc.w);
  }
  for (int ci = 128; ci < deg; ++ci){
    int s = csrc[s0 + ci];
    float a  = aS[(size_t)s * 4 + head];
    float ef = __expf(lrelu(a + adh) - mh);
    den += ef;
    float4 x2 = bf4(&xh[(size_t)s * 256 + c0]);
    acc.x = fmaf(ef, x2.x, acc.x);
    acc.y = fmaf(ef, x2.y, acc.y);
    acc.z = fmaf(ef, x2.z, acc.z);
    acc.w = fmaf(ef, x2.w, acc.w);
  }

  float inv = 1.f / den;
  float4 bb = *(const float4*)&bias[c0];
  float4 o;
  o.x = acc.x * inv + bb.x;
  o.y = acc.y * inv + bb.y;
  o.z = acc.z * inv + bb.z;
  o.w = acc.w * inv + bb.w;
  if constexpr (SCORE){
    float4 wvv = *(const float4*)&Wo[c0];
    float p = o.x * wvv.x + o.y * wvv.y + o.z * wvv.z + o.w * wvv.w;
#pragma unroll
    for (int mm = 1; mm < 64; mm <<= 1) p += __shfl_xor(p, mm, 64);
    if (lane == 0) out[n] = p + bo[0];
  } else {
    ushort4 hi, lo;
    unsigned short h;
    h = bfhi(o.x); hi.x = h; lo.x = bfhi(o.x - bf2f(h));
    h = bfhi(o.y); hi.y = h; lo.y = bfhi(o.y - bf2f(h));
    h = bfhi(o.z); hi.z = h; lo.z = bfhi(o.z - bf2f(h));
    h = bfhi(o.w); hi.w = h; lo.w = bfhi(o.w - bf2f(h));
    *(ushort4*)&h1hi[(size_t)n * 256 + c0] = hi;
    *(ushort4*)&h1lo[(size_t)n * 256 + c0] = lo;
  }
}

extern "C" void kernel_launch(void* const* d_in, const int* in_sizes, int n_in,
                              void* d_out, int out_size, void* d_ws, size_t ws_size,
                              hipStream_t stream)
{
  const float* x   = (const float*)d_in[0];
  const int*   ei  = (const int*)  d_in[1];
  const int*   ety = (const int*)  d_in[2];
  const float* ew  = (const float*)d_in[3];
  const float* rel = (const float*)d_in[4];
  const float* Wp  = (const float*)d_in[5];
  const float* bp  = (const float*)d_in[6];
  const float* W1  = (const float*)d_in[7];
  const float* as1 = (const float*)d_in[8];
  const float* ad1 = (const float*)d_in[9];
  const float* b1  = (const float*)d_in[10];
  const float* W2  = (const float*)d_in[11];
  const float* as2 = (const float*)d_in[12];
  const float* ad2 = (const float*)d_in[13];
  const float* b2  = (const float*)d_in[14];
  const float* Wo  = (const float*)d_in[15];
  const float* bo  = (const float*)d_in[16];
  float* out = (float*)d_out;

  const int N = N_NODES, E = E_EDGES;
  char* w = (char*)d_ws;
  size_t o = 0;
  auto alloc = [&](size_t bytes) -> char* {
    char* p = w + o;
    o = (o + bytes + 255) & ~(size_t)255;
    return p;
  };
  unsigned short* h0b  = (unsigned short*)alloc((size_t)N * 256 * 2);
  unsigned short* xhb  = (unsigned short*)alloc((size_t)N * 256 * 2);
  unsigned short* h1hi = (unsigned short*)alloc((size_t)N * 256 * 2);
  unsigned short* h1lo = (unsigned short*)alloc((size_t)N * 256 * 2);
  float* aS  = (float*)alloc((size_t)N * 4 * 4);
  float* aD  = (float*)alloc((size_t)N * 4 * 4);
  int* deg   = (int*)alloc((size_t)N * 4);
  int* offs  = (int*)alloc((size_t)(N + 1) * 4);
  int* cur   = (int*)alloc((size_t)N * 4);
  int* bsum  = (int*)alloc((size_t)128 * 4);
  int* csrc  = (int*)alloc((size_t)E * 4);
  int* cet   = (int*)alloc((size_t)E * 4);
  float* cw  = (float*)alloc((size_t)E * 4);
  unsigned short* BpP = (unsigned short*)alloc((size_t)2 * 896 * 256 * 2);
  unsigned short* Bp1 = (unsigned short*)alloc((size_t)2 * 256 * 256 * 2);
  unsigned short* Bp2 = (unsigned short*)alloc((size_t)2 * 256 * 256 * 2);

  const int* srcp = ei;
  const int* dstp = ei + E;

  const int nb = (N + 255) / 256;    // 79

  hipMemsetAsync(deg, 0, (size_t)N * 4, stream);
  k_count<<<(E + 255) / 256, 256, 0, stream>>>(dstp, deg, E);
  k_scan1<<<nb, 256, 0, stream>>>(deg, offs, bsum, N);
  k_scan2<<<1, 64, 0, stream>>>(bsum, nb, &offs[N]);
  k_scan3<<<nb, 256, 0, stream>>>(offs, bsum, cur, N);
  k_fill<<<(E + 255) / 256, 256, 0, stream>>>(srcp, dstp, ety, ew, offs, cur, csrc, cet, cw, E);

  // all three weight preps in one dispatch
  k_prep3<<<dim3(44, 4), 64, 0, stream>>>(Wp, W1, W2, BpP, Bp1, Bp2);

  const int gmm = N_NODES / 32;     // 625
  int nblk = (N + 3) / 4;

  // h0 = relu(xc @ Wp + bp) -> bf16  (single dispatch, frozen)
  k_mmp<<<dim3(gmm, 2), 128, 0, stream>>>(x, BpP, bp, h0b);
  // h1 = h0 + sum_in(h0[src] + rel*w) -> split planes
  k_agg<<<nblk, 256, 0, stream>>>(h0b, offs, csrc, cet, cw, rel, h1hi, h1lo, N);
  // GAT layer 1
  k_mmh<<<gmm, 256, 0, stream>>>(h1hi, h1lo, Bp1, xhb, as1, ad1, aS, aD);
  k_gat<false><<<nblk, 256, 0, stream>>>(xhb, aS, aD, offs, csrc, b1, h1hi, h1lo, nullptr, nullptr, nullptr, N);
  // GAT layer 2 + fused score
  k_mmh<<<gmm, 256, 0, stream>>>(h1hi, h1lo, Bp2, xhb, as2, ad2, aS, aD);
  k_gat<true><<<nblk, 256, 0, stream>>>(xhb, aS, aD, offs, csrc, b2, nullptr, nullptr, Wo, bo, out, N);
}

// Round 20
// 238.692 us; speedup vs baseline: 1.0503x; 1.0503x over previous
//
#include <hip/hip_runtime.h>
#include <hip/hip_bf16.h>

#define N_NODES 20000
#define E_EDGES 320000

typedef __attribute__((ext_vector_type(8))) short s8v;
typedef __attribute__((ext_vector_type(4))) float f4v;

__device__ __forceinline__ float lrelu(float v){ return v > 0.f ? v : 0.2f * v; }

__device__ __forceinline__ float bitf(unsigned short u){
  union { unsigned int i; float f; } v; v.i = ((unsigned int)u) << 16; return v.f;
}
__device__ __forceinline__ float4 bf4(const unsigned short* p){
  ushort4 u = *(const ushort4*)p;
  return make_float4(bitf(u.x), bitf(u.y), bitf(u.z), bitf(u.w));
}
__device__ __forceinline__ unsigned short bfhi(float v){
  union{float f; unsigned u;} a; a.f = v;
  unsigned r = a.u + 0x7FFFu + ((a.u >> 16) & 1u);
  return (unsigned short)(r >> 16);
}
__device__ __forceinline__ float bf2f(unsigned short h){
  union{unsigned u; float f;} a; a.u = ((unsigned)h) << 16; return a.f;
}
// split pair (v0,v1) into packed-bf16 hi word and lo word (RNE)
__device__ __forceinline__ void split2(float v0, float v1, unsigned& hu, unsigned& lu){
  __hip_bfloat162 h2 = __float22bfloat162_rn(make_float2(v0, v1));
  unsigned h; __builtin_memcpy(&h, &h2, 4);
  union{unsigned u; float f;} c0, c1;
  c0.u = h << 16;
  c1.u = h & 0xFFFF0000u;
  __hip_bfloat162 l2 = __float22bfloat162_rn(make_float2(v0 - c0.f, v1 - c1.f));
  unsigned l; __builtin_memcpy(&l, &l2, 4);
  hu = h; lu = l;
}
// async global->LDS, 16B per lane; lds base must be wave-uniform
__device__ __forceinline__ void gl_lds16(const void* g, void* l){
  __builtin_amdgcn_global_load_lds(
      (const __attribute__((address_space(1))) unsigned int*)g,
      (__attribute__((address_space(3))) unsigned int*)l, 16, 0, 0);
}

// ---------------- CSR build ----------------
__global__ __launch_bounds__(256) void k_count(const int* __restrict__ dst, int* __restrict__ deg, int E){
  int e = blockIdx.x * 256 + threadIdx.x;
  if (e < E) atomicAdd(&deg[dst[e]], 1);
}

// parallel scan stage 1: per-block exclusive scan + block sums (wave shfl scan)
__global__ __launch_bounds__(256) void k_scan1(const int* __restrict__ deg, int* __restrict__ off,
                                               int* __restrict__ bsum, int n){
  int b = blockIdx.x, t = threadIdx.x;
  int i = b * 256 + t;
  int lane = t & 63, w = t >> 6;
  int d = (i < n) ? deg[i] : 0;
  int x = d;
#pragma unroll
  for (int o = 1; o < 64; o <<= 1){
    int v = __shfl_up(x, o, 64);
    if (lane >= o) x += v;
  }
  __shared__ int ws[4];
  if (lane == 63) ws[w] = x;
  __syncthreads();
  int add = 0;
#pragma unroll
  for (int k = 0; k < 4; ++k) if (k < w) add += ws[k];
  x += add;
  if (i < n) off[i] = x - d;           // exclusive within block
  if (t == 255) bsum[b] = x;           // block total
}

// stage 2: tiny serial scan of block sums; also writes off[n] = total
__global__ __launch_bounds__(64) void k_scan2(int* __restrict__ bsum, int nb, int* __restrict__ offN){
  if (threadIdx.x == 0){
    int a = 0;
    for (int i = 0; i < nb; ++i){ int v = bsum[i]; bsum[i] = a; a += v; }
    *offN = a;
  }
}

// stage 3: add block bases; init cur
__global__ __launch_bounds__(256) void k_scan3(int* __restrict__ off, const int* __restrict__ bsum,
                                               int* __restrict__ cur, int n){
  int b = blockIdx.x, i = b * 256 + threadIdx.x;
  if (i < n){ off[i] += bsum[b]; cur[i] = 0; }
}

__global__ __launch_bounds__(256) void k_fill(const int* __restrict__ src, const int* __restrict__ dst,
                       const int* __restrict__ ety, const float* __restrict__ ew,
                       const int* __restrict__ off, int* __restrict__ cur,
                       int* __restrict__ csrc, int* __restrict__ cet, float* __restrict__ cw, int E){
  int e = blockIdx.x * 256 + threadIdx.x;
  if (e < E){
    int d = dst[e];
    int p = atomicAdd(&cur[d], 1);
    int i = off[d] + p;
    csrc[i] = src[e];
    cet[i]  = ety[e];
    cw[i]   = ew[e];
  }
}

// ---------------- combined weight prep: all three weight matrices in ONE dispatch ----------------
__global__ __launch_bounds__(64) void k_prep3(
    const float* __restrict__ Wp, const float* __restrict__ W1, const float* __restrict__ W2,
    unsigned short* __restrict__ BpP, unsigned short* __restrict__ Bp1, unsigned short* __restrict__ Bp2)
{
  int ktg = blockIdx.x;
  const float* W; unsigned short* Bp; int kt; int K;
  if (ktg < 28)      { W = Wp; Bp = BpP; kt = ktg;      K = 896; }
  else if (ktg < 36) { W = W1; Bp = Bp1; kt = ktg - 28; K = 256; }
  else               { W = W2; Bp = Bp2; kt = ktg - 36; K = 256; }
  int n = blockIdx.y * 64 + threadIdx.x;
  unsigned short hi[32], lo[32];
#pragma unroll
  for (int kk = 0; kk < 32; ++kk){
    float v = W[(size_t)(kt * 32 + kk) * 256 + n];   // coalesced over n
    unsigned short h = bfhi(v);
    hi[kk] = h;
    lo[kk] = bfhi(v - bf2f(h));
  }
  size_t plane = (size_t)(K >> 5) * 256 * 32;
  size_t b = ((size_t)kt * 256 + n) * 32;
#pragma unroll
  for (int kk = 0; kk < 32; ++kk){
    Bp[b + kk]         = hi[kk];
    Bp[plane + b + kk] = lo[kk];
  }
}

// ---------------- proj GEMM: R8/R12 kernel, single dispatch (62us; frozen) ----------------
__global__ __launch_bounds__(128, 4) void k_mmp(
    const float* __restrict__ A, const unsigned short* __restrict__ Bp,
    const float* __restrict__ bias, unsigned short* __restrict__ Cout)
{
  constexpr int KT = 28;
  __shared__ unsigned short AhB[2][32 * 40];
  __shared__ unsigned short AlB[2][32 * 40];

  const int tid  = threadIdx.x;
  const int lane = tid & 63;
  const int wn   = tid >> 6;
  const int l15  = lane & 15;
  const int kg   = lane >> 4;
  const int m0   = blockIdx.x * 32;
  const int n0   = blockIdx.y * 128;
  const size_t planeB = (size_t)KT * 256 * 32;

  f4v acc[2][4];
#pragma unroll
  for (int f = 0; f < 2; ++f)
#pragma unroll
    for (int g = 0; g < 4; ++g)
#pragma unroll
      for (int r = 0; r < 4; ++r) acc[f][g][r] = 0.f;

  const int arow = tid >> 2;          // 0..31 staged row
  const int aj   = tid & 3;           // k-chunk
  const int gr   = m0 + arow;

  auto loadA = [&](float* v, int kt){
    int c = kt * 32 + aj * 8;         // 8-chunks never straddle c=128
    const float* sp; float sc;
    if (c < 128){ sp = A + (size_t)gr * 896 + (768 + c); sc = 1.f; }
    else        { sp = A + (size_t)gr * 896 + (c - 128); sc = 3.f; }
    float4 f0 = *(const float4*)sp;
    float4 f1 = *(const float4*)(sp + 4);
    v[0]=f0.x*sc; v[1]=f0.y*sc; v[2]=f0.z*sc; v[3]=f0.w*sc;
    v[4]=f1.x*sc; v[5]=f1.y*sc; v[6]=f1.z*sc; v[7]=f1.w*sc;
  };
  auto writeLDS = [&](const float* v, int buf){
    union { unsigned u[4]; s8v s; } hv, lv;
#pragma unroll
    for (int p = 0; p < 4; ++p)
      split2(v[2*p], v[2*p+1], hv.u[p], lv.u[p]);
    *(s8v*)&AhB[buf][arow * 40 + aj * 8] = hv.s;
    *(s8v*)&AlB[buf][arow * 40 + aj * 8] = lv.s;
  };

  float av[8];
  loadA(av, 0);
  writeLDS(av, 0);
  loadA(av, 1);

  int cur = 0;
#pragma unroll 1
  for (int kt = 0; kt < KT; ++kt){
    __syncthreads();                       // LDS[cur] ready; LDS[cur^1] free
    if (kt + 1 < KT) writeLDS(av, cur ^ 1);
    if (kt + 2 < KT) loadA(av, kt + 2);
    s8v bh[4], bl[4];
#pragma unroll
    for (int g = 0; g < 4; ++g){
      const unsigned short* bp2 = Bp + ((size_t)kt * 256 + n0 + wn * 64 + g * 16 + l15) * 32 + kg * 8;
      bh[g] = *(const s8v*)bp2;
      bl[g] = *(const s8v*)(bp2 + planeB);
    }
    s8v ah[2], al[2];
#pragma unroll
    for (int f = 0; f < 2; ++f){
      int row = f * 16 + l15;
      ah[f] = *(const s8v*)&AhB[cur][row * 40 + kg * 8];
      al[f] = *(const s8v*)&AlB[cur][row * 40 + kg * 8];
    }
#pragma unroll
    for (int f = 0; f < 2; ++f)
#pragma unroll
      for (int g = 0; g < 4; ++g){
        acc[f][g] = __builtin_amdgcn_mfma_f32_16x16x32_bf16(ah[f], bh[g], acc[f][g], 0, 0, 0);
        acc[f][g] = __builtin_amdgcn_mfma_f32_16x16x32_bf16(ah[f], bl[g], acc[f][g], 0, 0, 0);
        acc[f][g] = __builtin_amdgcn_mfma_f32_16x16x32_bf16(al[f], bh[g], acc[f][g], 0, 0, 0);
      }
    cur ^= 1;
  }

#pragma unroll
  for (int f = 0; f < 2; ++f){
#pragma unroll
    for (int g = 0; g < 4; ++g){
      int col = n0 + wn * 64 + g * 16 + l15;
      float bb = bias[col];
#pragma unroll
      for (int r = 0; r < 4; ++r){
        int row = m0 + f * 16 + kg * 4 + r;
        float v = fmaxf(acc[f][g][r] + bb, 0.f);
        Cout[(size_t)row * 256 + col] = bfhi(v);
      }
    }
  }
}

// ---------------- hidden GEMM: global_load_lds + pre-split planes (BM=32, BN=256) ------------
__global__ __launch_bounds__(256, 2) void k_mmh(
    const unsigned short* __restrict__ Ahi, const unsigned short* __restrict__ Alo,
    const unsigned short* __restrict__ Bp, unsigned short* __restrict__ Cout,
    const float* __restrict__ attS, const float* __restrict__ attD,
    float* __restrict__ aS, float* __restrict__ aD)
{
  constexpr int KT = 8;
  __shared__ alignas(16) unsigned char Abuf[2][4096];

  const int tid  = threadIdx.x;
  const int lane = tid & 63;
  const int w    = tid >> 6;      // wave id = head
  const int l15  = lane & 15;
  const int kg   = lane >> 4;
  const int m0   = blockIdx.x * 32;
  const size_t planeB = (size_t)KT * 256 * 32;

  f4v acc[2][4];
#pragma unroll
  for (int f = 0; f < 2; ++f)
#pragma unroll
    for (int g = 0; g < 4; ++g)
#pragma unroll
      for (int r = 0; r < 4; ++r) acc[f][g][r] = 0.f;

  auto stage = [&](int buf, int kt){
    int s   = tid;
    int p   = s >> 7;
    int sp  = s & 127;
    int row = sp >> 2;
    int kcp = sp & 3;
    int kc  = kcp ^ (row & 3);        // inverse swizzle on SOURCE
    const unsigned short* basep = p ? Alo : Ahi;
    const unsigned short* gp = basep + (size_t)(m0 + row) * 256 + kt * 32 + kc * 8;
    gl_lds16(gp, &Abuf[buf][w * 1024]);
  };
  auto readFrags = [&](s8v* ah, s8v* al, int buf){
#pragma unroll
    for (int f = 0; f < 2; ++f){
      int row = f * 16 + l15;
      int kc  = kg ^ (row & 3);       // swizzled read
      ah[f] = *(const s8v*)&Abuf[buf][row * 64 + kc * 16];
      al[f] = *(const s8v*)&Abuf[buf][2048 + row * 64 + kc * 16];
    }
  };
  auto loadB = [&](s8v* bh, s8v* bl, int kt){
#pragma unroll
    for (int g = 0; g < 4; ++g){
      const unsigned short* bp2 = Bp + ((size_t)kt * 256 + w * 64 + g * 16 + l15) * 32 + kg * 8;
      bh[g] = *(const s8v*)bp2;
      bl[g] = *(const s8v*)(bp2 + planeB);
    }
  };
  auto doMFMA = [&](const s8v* ah, const s8v* al, const s8v* bh, const s8v* bl){
#pragma unroll
    for (int f = 0; f < 2; ++f)
#pragma unroll
      for (int g = 0; g < 4; ++g){
        acc[f][g] = __builtin_amdgcn_mfma_f32_16x16x32_bf16(ah[f], bh[g], acc[f][g], 0, 0, 0);
        acc[f][g] = __builtin_amdgcn_mfma_f32_16x16x32_bf16(ah[f], bl[g], acc[f][g], 0, 0, 0);
        acc[f][g] = __builtin_amdgcn_mfma_f32_16x16x32_bf16(al[f], bh[g], acc[f][g], 0, 0, 0);
      }
  };

  s8v bh[4], bl[4];
  stage(0, 0);
  loadB(bh, bl, 0);
  __syncthreads();

  int cur = 0;
#pragma unroll 1
  for (int kt = 0; kt < KT; ++kt){
    if (kt + 1 < KT) stage(cur ^ 1, kt + 1);   // async, zero regs
    s8v ah[2], al[2];
    readFrags(ah, al, cur);
    s8v nbh[4], nbl[4];
    if (kt + 1 < KT) loadB(nbh, nbl, kt + 1);
    doMFMA(ah, al, bh, bl);
    if (kt + 1 < KT){
#pragma unroll
      for (int g = 0; g < 4; ++g){ bh[g] = nbh[g]; bl[g] = nbl[g]; }
    }
    __syncthreads();
    cur ^= 1;
  }

#pragma unroll
  for (int f = 0; f < 2; ++f){
#pragma unroll
    for (int g = 0; g < 4; ++g){
      int col = w * 64 + g * 16 + l15;
#pragma unroll
      for (int r = 0; r < 4; ++r){
        int row = m0 + f * 16 + kg * 4 + r;
        Cout[(size_t)row * 256 + col] = bfhi(acc[f][g][r]);
      }
    }
  }

  {
    const int head = w;
    float sv[4], dv[4];
#pragma unroll
    for (int g = 0; g < 4; ++g){
      int col = w * 64 + g * 16 + l15;
      sv[g] = attS[col];
      dv[g] = attD[col];
    }
#pragma unroll
    for (int f = 0; f < 2; ++f){
#pragma unroll
      for (int r = 0; r < 4; ++r){
        float ps = acc[f][0][r]*sv[0] + acc[f][1][r]*sv[1] + acc[f][2][r]*sv[2] + acc[f][3][r]*sv[3];
        float pd = acc[f][0][r]*dv[0] + acc[f][1][r]*dv[1] + acc[f][2][r]*dv[2] + acc[f][3][r]*dv[3];
#pragma unroll
        for (int mm = 1; mm < 16; mm <<= 1){
          ps += __shfl_xor(ps, mm, 64);
          pd += __shfl_xor(pd, mm, 64);
        }
        int row = m0 + f * 16 + kg * 4 + r;
        if (l15 == 0){
          aS[(size_t)row * 4 + head] = ps;
          aD[(size_t)row * 4 + head] = pd;
        }
      }
    }
  }
}

// ---------------- first aggregation: h1 = h0[n] + Σ h0[src] + Σ_t wsum_t*rel[t] ----------------
__global__ __launch_bounds__(256) void k_agg(
    const unsigned short* __restrict__ h0, const int* __restrict__ off,
    const int* __restrict__ csrc, const int* __restrict__ cet, const float* __restrict__ cw,
    const float* __restrict__ rel,
    unsigned short* __restrict__ h1hi, unsigned short* __restrict__ h1lo, int N)
{
  __shared__ int srcs[4][128];
  const int wv = threadIdx.x >> 6;
  const int n  = blockIdx.x * 4 + wv;
  if (n >= N) return;
  const int lane = threadIdx.x & 63;
  const int c0 = lane * 4;
  const int s0 = off[n], s1 = off[n + 1];
  const int deg = s1 - s0;
  const int nc = deg < 128 ? deg : 128;

  float w0=0.f, w1=0.f, w2=0.f, w3=0.f, w4=0.f;
  for (int base = 0; base < deg; base += 64){
    int ci = base + lane;
    if (ci < deg){
      int e = s0 + ci;
      int s = csrc[e];
      int t = cet[e];
      float wg = cw[e];
      if (ci < 128) srcs[wv][ci] = s;
      w0 += (t == 0) ? wg : 0.f;
      w1 += (t == 1) ? wg : 0.f;
      w2 += (t == 2) ? wg : 0.f;
      w3 += (t == 3) ? wg : 0.f;
      w4 += (t == 4) ? wg : 0.f;
    }
  }
#pragma unroll
  for (int mm = 1; mm < 64; mm <<= 1){
    w0 += __shfl_xor(w0, mm, 64);
    w1 += __shfl_xor(w1, mm, 64);
    w2 += __shfl_xor(w2, mm, 64);
    w3 += __shfl_xor(w3, mm, 64);
    w4 += __shfl_xor(w4, mm, 64);
  }
  asm volatile("s_waitcnt lgkmcnt(0)" ::: "memory");   // srcs visible in-wave

  float4 acc = bf4(&h0[(size_t)n * 256 + c0]);
  { float4 R = *(const float4*)&rel[0 * 256 + c0];
    acc.x = fmaf(w0, R.x, acc.x); acc.y = fmaf(w0, R.y, acc.y);
    acc.z = fmaf(w0, R.z, acc.z); acc.w = fmaf(w0, R.w, acc.w); }
  { float4 R = *(const float4*)&rel[1 * 256 + c0];
    acc.x = fmaf(w1, R.x, acc.x); acc.y = fmaf(w1, R.y, acc.y);
    acc.z = fmaf(w1, R.z, acc.z); acc.w = fmaf(w1, R.w, acc.w); }
  { float4 R = *(const float4*)&rel[2 * 256 + c0];
    acc.x = fmaf(w2, R.x, acc.x); acc.y = fmaf(w2, R.y, acc.y);
    acc.z = fmaf(w2, R.z, acc.z); acc.w = fmaf(w2, R.w, acc.w); }
  { float4 R = *(const float4*)&rel[3 * 256 + c0];
    acc.x = fmaf(w3, R.x, acc.x); acc.y = fmaf(w3, R.y, acc.y);
    acc.z = fmaf(w3, R.z, acc.z); acc.w = fmaf(w3, R.w, acc.w); }
  { float4 R = *(const float4*)&rel[4 * 256 + c0];
    acc.x = fmaf(w4, R.x, acc.x); acc.y = fmaf(w4, R.y, acc.y);
    acc.z = fmaf(w4, R.z, acc.z); acc.w = fmaf(w4, R.w, acc.w); }

  int e = 0;
  for (; e + 7 < nc; e += 8){
    int sA = srcs[wv][e  ], sB = srcs[wv][e+1], sC = srcs[wv][e+2], sD = srcs[wv][e+3];
    int sE = srcs[wv][e+4], sF = srcs[wv][e+5], sG = srcs[wv][e+6], sH = srcs[wv][e+7];
    float4 xA = bf4(&h0[(size_t)sA * 256 + c0]);
    float4 xB = bf4(&h0[(size_t)sB * 256 + c0]);
    float4 xC = bf4(&h0[(size_t)sC * 256 + c0]);
    float4 xD = bf4(&h0[(size_t)sD * 256 + c0]);
    float4 xE = bf4(&h0[(size_t)sE * 256 + c0]);
    float4 xF = bf4(&h0[(size_t)sF * 256 + c0]);
    float4 xG = bf4(&h0[(size_t)sG * 256 + c0]);
    float4 xH = bf4(&h0[(size_t)sH * 256 + c0]);
    acc.x += ((xA.x + xB.x) + (xC.x + xD.x)) + ((xE.x + xF.x) + (xG.x + xH.x));
    acc.y += ((xA.y + xB.y) + (xC.y + xD.y)) + ((xE.y + xF.y) + (xG.y + xH.y));
    acc.z += ((xA.z + xB.z) + (xC.z + xD.z)) + ((xE.z + xF.z) + (xG.z + xH.z));
    acc.w += ((xA.w + xB.w) + (xC.w + xD.w)) + ((xE.w + xF.w) + (xG.w + xH.w));
  }
  for (; e < nc; ++e){
    int s = srcs[wv][e];
    float4 xv = bf4(&h0[(size_t)s * 256 + c0]);
    acc.x += xv.x; acc.y += xv.y; acc.z += xv.z; acc.w += xv.w;
  }
  for (int ci = 128; ci < deg; ++ci){    // overflow (wsum already complete)
    int s = csrc[s0 + ci];
    float4 xv = bf4(&h0[(size_t)s * 256 + c0]);
    acc.x += xv.x; acc.y += xv.y; acc.z += xv.z; acc.w += xv.w;
  }

  ushort4 hi, lo;
  { unsigned short h;
    h = bfhi(acc.x); hi.x = h; lo.x = bfhi(acc.x - bf2f(h));
    h = bfhi(acc.y); hi.y = h; lo.y = bfhi(acc.y - bf2f(h));
    h = bfhi(acc.z); hi.z = h; lo.z = bfhi(acc.z - bf2f(h));
    h = bfhi(acc.w); hi.w = h; lo.w = bfhi(acc.w - bf2f(h));
  }
  *(ushort4*)&h1hi[(size_t)n * 256 + c0] = hi;
  *(ushort4*)&h1lo[(size_t)n * 256 + c0] = lo;
}

// ---------------- GAT edge softmax + aggregate; 8-deep gather MLP ----------------
template<bool SCORE>
__global__ __launch_bounds__(256) void k_gat(
    const unsigned short* __restrict__ xh, const float* __restrict__ aS, const float* __restrict__ aD,
    const int* __restrict__ off, const int* __restrict__ csrc,
    const float* __restrict__ bias,
    unsigned short* __restrict__ h1hi, unsigned short* __restrict__ h1lo,
    const float* __restrict__ Wo, const float* __restrict__ bo, float* __restrict__ out, int N)
{
  __shared__ float4 exs[4][128];
  __shared__ int   srcs[4][128];
  const int wv   = threadIdx.x >> 6;
  const int n    = blockIdx.x * 4 + wv;
  if (n >= N) return;
  const int lane = threadIdx.x & 63;
  const int head = lane >> 4;
  const int c0   = lane * 4;
  const int s0 = off[n], s1 = off[n + 1];
  const int deg = s1 - s0;
  const int nc = deg < 128 ? deg : 128;

  float4 ad4 = *(const float4*)&aD[(size_t)n * 4];
  float4 asf = *(const float4*)&aS[(size_t)n * 4];
  float4 aself;
  aself.x = lrelu(asf.x + ad4.x); aself.y = lrelu(asf.y + ad4.y);
  aself.z = lrelu(asf.z + ad4.z); aself.w = lrelu(asf.w + ad4.w);
  float4 q = aself;

  for (int base = 0; base < deg; base += 64){
    int ci = base + lane;
    if (ci < deg){
      int s = csrc[s0 + ci];
      float4 av = *(const float4*)&aS[(size_t)s * 4];
      float4 al4;
      al4.x = lrelu(av.x + ad4.x); al4.y = lrelu(av.y + ad4.y);
      al4.z = lrelu(av.z + ad4.z); al4.w = lrelu(av.w + ad4.w);
      q.x = fmaxf(q.x, al4.x); q.y = fmaxf(q.y, al4.y);
      q.z = fmaxf(q.z, al4.z); q.w = fmaxf(q.w, al4.w);
      if (ci < 128){ srcs[wv][ci] = s; exs[wv][ci] = al4; }
    }
  }
#pragma unroll
  for (int mm = 1; mm < 64; mm <<= 1){
    q.x = fmaxf(q.x, __shfl_xor(q.x, mm, 64));
    q.y = fmaxf(q.y, __shfl_xor(q.y, mm, 64));
    q.z = fmaxf(q.z, __shfl_xor(q.z, mm, 64));
    q.w = fmaxf(q.w, __shfl_xor(q.w, mm, 64));
  }
  asm volatile("s_waitcnt lgkmcnt(0)" ::: "memory");

  float4 den4 = make_float4(0.f, 0.f, 0.f, 0.f);
  for (int ci = lane; ci < nc; ci += 64){
    float4 a = exs[wv][ci];
    float4 e4;
    e4.x = __expf(a.x - q.x); e4.y = __expf(a.y - q.y);
    e4.z = __expf(a.z - q.z); e4.w = __expf(a.w - q.w);
    exs[wv][ci] = e4;
    den4.x += e4.x; den4.y += e4.y; den4.z += e4.z; den4.w += e4.w;
  }
#pragma unroll
  for (int mm = 1; mm < 64; mm <<= 1){
    den4.x += __shfl_xor(den4.x, mm, 64);
    den4.y += __shfl_xor(den4.y, mm, 64);
    den4.z += __shfl_xor(den4.z, mm, 64);
    den4.w += __shfl_xor(den4.w, mm, 64);
  }
  asm volatile("s_waitcnt lgkmcnt(0)" ::: "memory");

  const float mh  = head == 0 ? q.x : (head == 1 ? q.y : (head == 2 ? q.z : q.w));
  const float adh = head == 0 ? ad4.x : (head == 1 ? ad4.y : (head == 2 ? ad4.z : ad4.w));
  const float aselfh = head == 0 ? aself.x : (head == 1 ? aself.y : (head == 2 ? aself.z : aself.w));
  float den = (head == 0 ? den4.x : (head == 1 ? den4.y : (head == 2 ? den4.z : den4.w)));
  float exself = __expf(aselfh - mh);
  den += exself;

  float4 xv = bf4(&xh[(size_t)n * 256 + c0]);
  float4 acc;
  acc.x = exself * xv.x; acc.y = exself * xv.y; acc.z = exself * xv.z; acc.w = exself * xv.w;

  const float* exw = (const float*)&exs[wv][0];
  int e = 0;
  for (; e + 7 < nc; e += 8){
    int sA = srcs[wv][e  ], sB = srcs[wv][e+1], sC = srcs[wv][e+2], sD = srcs[wv][e+3];
    int sE = srcs[wv][e+4], sF = srcs[wv][e+5], sG = srcs[wv][e+6], sH = srcs[wv][e+7];
    float eA = exw[(e  ) * 4 + head], eB = exw[(e+1) * 4 + head];
    float eC = exw[(e+2) * 4 + head], eD = exw[(e+3) * 4 + head];
    float eE = exw[(e+4) * 4 + head], eF = exw[(e+5) * 4 + head];
    float eG = exw[(e+6) * 4 + head], eH = exw[(e+7) * 4 + head];
    float4 xA = bf4(&xh[(size_t)sA * 256 + c0]);
    float4 xB = bf4(&xh[(size_t)sB * 256 + c0]);
    float4 xC = bf4(&xh[(size_t)sC * 256 + c0]);
    float4 xD = bf4(&xh[(size_t)sD * 256 + c0]);
    float4 xE = bf4(&xh[(size_t)sE * 256 + c0]);
    float4 xF = bf4(&xh[(size_t)sF * 256 + c0]);
    float4 xG = bf4(&xh[(size_t)sG * 256 + c0]);
    float4 xH = bf4(&xh[(size_t)sH * 256 + c0]);
    float t0, t1, t2, t3;
    t0 = eA*xA.x + eB*xB.x; t1 = eC*xC.x + eD*xD.x; t2 = eE*xE.x + eF*xF.x; t3 = eG*xG.x + eH*xH.x;
    acc.x += (t0 + t1) + (t2 + t3);
    t0 = eA*xA.y + eB*xB.y; t1 = eC*xC.y + eD*xD.y; t2 = eE*xE.y + eF*xF.y; t3 = eG*xG.y + eH*xH.y;
    acc.y += (t0 + t1) + (t2 + t3);
    t0 = eA*xA.z + eB*xB.z; t1 = eC*xC.z + eD*xD.z; t2 = eE*xE.z + eF*xF.z; t3 = eG*xG.z + eH*xH.z;
    acc.z += (t0 + t1) + (t2 + t3);
    t0 = eA*xA.w + eB*xB.w; t1 = eC*xC.w + eD*xD.w; t2 = eE*xE.w + eF*xF.w; t3 = eG*xG.w + eH*xH.w;
    acc.w += (t0 + t1) + (t2 + t3);
  }
  for (; e < nc; ++e){
    int s = srcs[wv][e];
    float ef = exw[e * 4 + head];
    float4 x2 = bf4(&xh[(size_t)s * 256 + c0]);
    acc.x = fmaf(ef, x2.x, acc.x);
    acc.y = fmaf(ef, x2.y, acc.y);
    acc.z = fmaf(ef, x2.z, acc.z);
    acc.w = fmaf(ef, x2.w, acc.w);
  }
  for (int ci = 128; ci < deg; ++ci){
    int s = csrc[s0 + ci];
    float a  = aS[(size_t)s * 4 + head];
    float ef = __expf(lrelu(a + adh) - mh);
    den += ef;
    float4 x2 = bf4(&xh[(size_t)s * 256 + c0]);
    acc.x = fmaf(ef, x2.x, acc.x);
    acc.y = fmaf(ef, x2.y, acc.y);
    acc.z = fmaf(ef, x2.z, acc.z);
    acc.w = fmaf(ef, x2.w, acc.w);
  }

  float inv = 1.f / den;
  float4 bb = *(const float4*)&bias[c0];
  float4 o;
  o.x = acc.x * inv + bb.x;
  o.y = acc.y * inv + bb.y;
  o.z = acc.z * inv + bb.z;
  o.w = acc.w * inv + bb.w;
  if constexpr (SCORE){
    float4 wvv = *(const float4*)&Wo[c0];
    float p = o.x * wvv.x + o.y * wvv.y + o.z * wvv.z + o.w * wvv.w;
#pragma unroll
    for (int mm = 1; mm < 64; mm <<= 1) p += __shfl_xor(p, mm, 64);
    if (lane == 0) out[n] = p + bo[0];
  } else {
    ushort4 hi, lo;
    unsigned short h;
    h = bfhi(o.x); hi.x = h; lo.x = bfhi(o.x - bf2f(h));
    h = bfhi(o.y); hi.y = h; lo.y = bfhi(o.y - bf2f(h));
    h = bfhi(o.z); hi.z = h; lo.z = bfhi(o.z - bf2f(h));
    h = bfhi(o.w); hi.w = h; lo.w = bfhi(o.w - bf2f(h));
    *(ushort4*)&h1hi[(size_t)n * 256 + c0] = hi;
    *(ushort4*)&h1lo[(size_t)n * 256 + c0] = lo;
  }
}

extern "C" void kernel_launch(void* const* d_in, const int* in_sizes, int n_in,
                              void* d_out, int out_size, void* d_ws, size_t ws_size,
                              hipStream_t stream)
{
  const float* x   = (const float*)d_in[0];
  const int*   ei  = (const int*)  d_in[1];
  const int*   ety = (const int*)  d_in[2];
  const float* ew  = (const float*)d_in[3];
  const float* rel = (const float*)d_in[4];
  const float* Wp  = (const float*)d_in[5];
  const float* bp  = (const float*)d_in[6];
  const float* W1  = (const float*)d_in[7];
  const float* as1 = (const float*)d_in[8];
  const float* ad1 = (const float*)d_in[9];
  const float* b1  = (const float*)d_in[10];
  const float* W2  = (const float*)d_in[11];
  const float* as2 = (const float*)d_in[12];
  const float* ad2 = (const float*)d_in[13];
  const float* b2  = (const float*)d_in[14];
  const float* Wo  = (const float*)d_in[15];
  const float* bo  = (const float*)d_in[16];
  float* out = (float*)d_out;

  const int N = N_NODES, E = E_EDGES;
  char* w = (char*)d_ws;
  size_t o = 0;
  auto alloc = [&](size_t bytes) -> char* {
    char* p = w + o;
    o = (o + bytes + 255) & ~(size_t)255;
    return p;
  };
  unsigned short* h0b  = (unsigned short*)alloc((size_t)N * 256 * 2);
  unsigned short* xhb  = (unsigned short*)alloc((size_t)N * 256 * 2);
  unsigned short* h1hi = (unsigned short*)alloc((size_t)N * 256 * 2);
  unsigned short* h1lo = (unsigned short*)alloc((size_t)N * 256 * 2);
  float* aS  = (float*)alloc((size_t)N * 4 * 4);
  float* aD  = (float*)alloc((size_t)N * 4 * 4);
  int* deg   = (int*)alloc((size_t)N * 4);
  int* offs  = (int*)alloc((size_t)(N + 1) * 4);
  int* cur   = (int*)alloc((size_t)N * 4);
  int* bsum  = (int*)alloc((size_t)128 * 4);
  int* csrc  = (int*)alloc((size_t)E * 4);
  int* cet   = (int*)alloc((size_t)E * 4);
  float* cw  = (float*)alloc((size_t)E * 4);
  unsigned short* BpP = (unsigned short*)alloc((size_t)2 * 896 * 256 * 2);
  unsigned short* Bp1 = (unsigned short*)alloc((size_t)2 * 256 * 256 * 2);
  unsigned short* Bp2 = (unsigned short*)alloc((size_t)2 * 256 * 256 * 2);

  const int* srcp = ei;
  const int* dstp = ei + E;

  const int nb = (N + 255) / 256;    // 79

  hipMemsetAsync(deg, 0, (size_t)N * 4, stream);
  k_count<<<(E + 255) / 256, 256, 0, stream>>>(dstp, deg, E);
  k_scan1<<<nb, 256, 0, stream>>>(deg, offs, bsum, N);
  k_scan2<<<1, 64, 0, stream>>>(bsum, nb, &offs[N]);
  k_scan3<<<nb, 256, 0, stream>>>(offs, bsum, cur, N);
  k_fill<<<(E + 255) / 256, 256, 0, stream>>>(srcp, dstp, ety, ew, offs, cur, csrc, cet, cw, E);

  // all three weight preps in one dispatch
  k_prep3<<<dim3(44, 4), 64, 0, stream>>>(Wp, W1, W2, BpP, Bp1, Bp2);

  const int gmm = N_NODES / 32;     // 625
  int nblk = (N + 3) / 4;

  // h0 = relu(xc @ Wp + bp) -> bf16  (single dispatch, frozen)
  k_mmp<<<dim3(gmm, 2), 128, 0, stream>>>(x, BpP, bp, h0b);
  // h1 = h0 + sum_in(h0[src] + rel*w) -> split planes
  k_agg<<<nblk, 256, 0, stream>>>(h0b, offs, csrc, cet, cw, rel, h1hi, h1lo, N);
  // GAT layer 1
  k_mmh<<<gmm, 256, 0, stream>>>(h1hi, h1lo, Bp1, xhb, as1, ad1, aS, aD);
  k_gat<false><<<nblk, 256, 0, stream>>>(xhb, aS, aD, offs, csrc, b1, h1hi, h1lo, nullptr, nullptr, nullptr, N);
  // GAT layer 2 + fused score
  k_mmh<<<gmm, 256, 0, stream>>>(h1hi, h1lo, Bp2, xhb, as2, ad2, aS, aD);
  k_gat<true><<<nblk, 256, 0, stream>>>(xhb, aS, aD, offs, csrc, b2, nullptr, nullptr, Wo, bo, out, N);
}